// Round 12
// baseline (420.223 us; speedup 1.0000x reference)
//
#include <hip/hip_runtime.h>

// PairwiseInteract, round 15: fused kernel + dual-tile (retry of r8's idea on
// the dieted register structure).
// r14 verdict: occupancy is NOT the limiter (2/3/4 waves/SIMD all plateau at
// MfmaUtil 57-66%). Per-CU arithmetic: MFMA = 184us of matrix-pipe, LDS =
// 262144 tiles x 32 ds_read_b128 x ~12cyc / 256 CU = 164us of LDS-pipe --
// comparable, serially coupled (reads feed MFMAs) -> ~350us walls.
// Fix: process TWO j-tiles per iteration; each weight-fragment read feeds 12
// MFMAs (4 independent chains) instead of 6 -> LDS/tile halves (164->82us,
// below the MFMA floor) and chain ILP doubles. Round-5's version of this
// spilled from a 188-reg baseline (+72 -> 260 > 256); the r13-fused baseline
// is 128 total, dual-tile -> ~196 <= 256 at __launch_bounds__(256,2).
// A-tile accumulated into sA before B-tile = r8's passing order.
// Tripwire: FETCH>5MB or WRITE>1MB = spill -> r13 is final.

#define NOBJ 1024
#define H 50
#define F 20

using short8 = __attribute__((ext_vector_type(8))) short;
using v16f   = __attribute__((ext_vector_type(16))) float;

#define MFMA(A, B, C) __builtin_amdgcn_mfma_f32_32x32x16_bf16((A), (B), (C), 0, 0, 0)

__device__ __forceinline__ float trunchi(float x) {
    return __uint_as_float(__float_as_uint(x) & 0xFFFF0000u);
}
// dword = hi16(a) in low half | hi16(b) in high half
__device__ __forceinline__ unsigned pkhi(float a, float b) {
    return __builtin_amdgcn_perm(__float_as_uint(b), __float_as_uint(a), 0x07060302u);
}
__device__ __forceinline__ short8 as_s8(uint4 v) {
    union { uint4 u; short8 s; } x; x.u = v; return x.s;
}
// out-neuron at C slot (mt, tile-row l)
__device__ __forceinline__ int nu(int mt, int l) {
    return 16 * (l >> 3) + 8 * ((l >> 2) & 1) + 4 * mt + (l & 3);
}

// full pack for k-frags 0..2 (all 48 neurons real there)
#define PACK_MT3(ACC, MT, XH, XL)                                             \
    _Pragma("unroll") for (int f_ = 0; f_ < 3; ++f_) {                        \
        float r0 = fmaxf((ACC)[4 * f_ + 0], 0.f);                             \
        float r1 = fmaxf((ACC)[4 * f_ + 1], 0.f);                             \
        float r2 = fmaxf((ACC)[4 * f_ + 2], 0.f);                             \
        float r3 = fmaxf((ACC)[4 * f_ + 3], 0.f);                             \
        float l0 = r0 - trunchi(r0), l1 = r1 - trunchi(r1);                   \
        float l2 = r2 - trunchi(r2), l3 = r3 - trunchi(r3);                   \
        ((unsigned*)&(XH)[f_])[2 * (MT) + 0] = pkhi(r0, r1);                  \
        ((unsigned*)&(XH)[f_])[2 * (MT) + 1] = pkhi(r2, r3);                  \
        ((unsigned*)&(XL)[f_])[2 * (MT) + 0] = pkhi(l0, l1);                  \
        ((unsigned*)&(XL)[f_])[2 * (MT) + 1] = pkhi(l2, l3);                  \
    }

// k-frag 3: only k=48,49 (h=0) live activations; k=50 = injected bias mult.
#define PACK_F3(ACC0, XH, XL, INJ)                                            \
    {                                                                         \
        float r0_ = fmaxf((ACC0)[12], 0.f);                                   \
        float r1_ = fmaxf((ACC0)[13], 0.f);                                   \
        float l0_ = r0_ - trunchi(r0_), l1_ = r1_ - trunchi(r1_);             \
        (XH)[3].x = pkhi(r0_, r1_); (XL)[3].x = pkhi(l0_, l1_);               \
        (XH)[3].y = (INJ); (XL)[3].y = 0u;                                    \
        (XH)[3].z = 0u; (XH)[3].w = 0u;                                       \
        (XL)[3].z = 0u; (XL)[3].w = 0u;                                       \
    }

#define LDSFRAG(id)  (*(const short8*)&wfrag[(id) * 64 + lane])
// opaque-index variant: obf (==0, but opaque per-iteration) blocks hoist/CSE
#define LDSFRAGO(id) (*(const short8*)&wfrag[((id) + obf) * 64 + lane])

// dual-tile hidden layer: per k-frag, 4 ds_read_b128 shared by 12 MFMA
// (tiles A,B x m-tiles 0,1 = 4 independent chains; per-chain order hh,hl,lh)
#define DUAL_CHAIN(BASEC, XAh, XAl, XBh, XBl)                                 \
    _Pragma("unroll") for (int f_ = 0; f_ < 4; ++f_) {                        \
        short8 ah0 = LDSFRAGO(((BASEC) + f_) * 2 + 0);                        \
        short8 al0 = LDSFRAGO(((BASEC) + f_) * 2 + 1);                        \
        short8 ah1 = LDSFRAGO(((BASEC) + 4 + f_) * 2 + 0);                    \
        short8 al1 = LDSFRAGO(((BASEC) + 4 + f_) * 2 + 1);                    \
        short8 bAh = as_s8((XAh)[f_]), bAl = as_s8((XAl)[f_]);                \
        short8 bBh = as_s8((XBh)[f_]), bBl = as_s8((XBl)[f_]);                \
        if (f_ == 0) {                                                        \
            aA0 = MFMA(ah0, bAh, zero16); aB0 = MFMA(ah0, bBh, zero16);       \
            aA1 = MFMA(ah1, bAh, zero16); aB1 = MFMA(ah1, bBh, zero16);       \
        } else {                                                              \
            aA0 = MFMA(ah0, bAh, aA0); aB0 = MFMA(ah0, bBh, aB0);             \
            aA1 = MFMA(ah1, bAh, aA1); aB1 = MFMA(ah1, bBh, aB1);             \
        }                                                                     \
        aA0 = MFMA(ah0, bAl, aA0); aB0 = MFMA(ah0, bBl, aB0);                 \
        aA1 = MFMA(ah1, bAl, aA1); aB1 = MFMA(ah1, bBl, aB1);                 \
        aA0 = MFMA(al0, bAh, aA0); aB0 = MFMA(al0, bBh, aB0);                 \
        aA1 = MFMA(al1, bAh, aA1); aB1 = MFMA(al1, bBh, aB1);                 \
    }

__global__ __launch_bounds__(256, 2)
void fused_kernel(const float* __restrict__ obj0, const float* __restrict__ obj1,
                  const float* __restrict__ prev0, const float* __restrict__ prev1,
                  const float* __restrict__ gW0, const float* __restrict__ gb0,
                  const float* __restrict__ gW1, const float* __restrict__ gb1,
                  const float* __restrict__ gW2, const float* __restrict__ gb2,
                  const float* __restrict__ gW3, const float* __restrict__ gb3,
                  const float* __restrict__ aW0, const float* __restrict__ ab0,
                  const float* __restrict__ aW1, const float* __restrict__ ab1,
                  float* __restrict__ out)
{
    // 36 pre-packed A-fragments (L1:0..15, L2:16..31, W0:32..35), 1KB each
    __shared__ uint4 wfrag[36 * 64];
    __shared__ float fbuf[2][F];     // per-block force accumulators

    const int w    = threadIdx.x >> 6;   // wave 0..3
    const int lane = threadIdx.x & 63;
    const int h    = lane >> 5;          // half-wave
    const int l31  = lane & 31;

    const int c  = blockIdx.y;           // actee class
    const int il = w >> 1;               // i_local 0/1
    const int i  = blockIdx.x * 2 + il;
    const int jh = w & 1;                // j-half

    const float* actee = (c == 0) ? obj0 : obj1;
    const float av  = actee[i];
    const float avl = av - trunchi(av);
    const unsigned inj   = (h == 0) ? 0x00003F80u : 0u;   // 1.0 bf16 at k=50
    const unsigned inj16 = (h == 0) ? 0x00004180u : 0u;   // 16.0 bf16 at k=50

    if (threadIdx.x < 2 * F) ((float*)fbuf)[threadIdx.x] = 0.f;

    const v16f zero16 = (v16f)0.0f;

#pragma unroll 1
    for (int a = 0; a < 4; ++a) {
        const int m = a * 2 + c;         // module
        const float* actor = (a == 0) ? obj0 : (a == 1) ? obj1
                           : (a == 2) ? prev0 : prev1;

        // ---- stage W0/W1/W2 split-bf16 A-fragments for module m ----
        for (int combo = w; combo < 18; combo += 4) {
            const int layer = (combo < 8) ? 1 : (combo < 16) ? 2 : 0;
            const float* W; const float* b; int ncols, col, mt, f, krows;
            if (layer == 1) {
                const int rel = combo;
                W = gW1 + m * H * H; b = gb1 + m * H; ncols = H; krows = H;
                mt = rel >> 2; f = rel & 3; col = nu(mt, l31);
            } else if (layer == 2) {
                const int rel = combo - 8;
                W = gW2 + m * H * H; b = gb2 + m * H; ncols = H; krows = H;
                mt = rel >> 2; f = rel & 3; col = nu(mt, l31);
            } else {
                const int rel = combo - 16;
                W = gW0 + m * 2 * H; b = gb0 + m * H; ncols = H; krows = 2;
                mt = rel; f = 0; col = nu(mt, l31);
            }
            unsigned hs[8], ls[8];
#pragma unroll
            for (int j = 0; j < 8; ++j) {
                const int k = 16 * f + 8 * h + j;
                float wv = 0.f;
                if (col < ncols) {
                    if (k < krows) wv = W[k * ncols + col];
                    else if (k == krows) wv = b[col];      // bias row
                }
                unsigned uh = __float_as_uint(wv) & 0xFFFF0000u;
                float lof = wv - __uint_as_float(uh);
                hs[j] = uh;
                ls[j] = __float_as_uint(lof) & 0xFFFF0000u;
            }
            uint4 hi, lo;
            hi.x = (hs[0] >> 16) | hs[1]; hi.y = (hs[2] >> 16) | hs[3];
            hi.z = (hs[4] >> 16) | hs[5]; hi.w = (hs[6] >> 16) | hs[7];
            lo.x = (ls[0] >> 16) | ls[1]; lo.y = (ls[2] >> 16) | ls[3];
            lo.z = (ls[4] >> 16) | ls[5]; lo.w = (ls[6] >> 16) | ls[7];
            wfrag[(combo * 2 + 0) * 64 + lane] = hi;
            wfrag[(combo * 2 + 1) * 64 + lane] = lo;
        }
        __syncthreads();                 // staging visible to all waves

        v16f sA0 = (v16f)0.0f, sA1 = (v16f)0.0f;   // sum of relu(h2)
        float xaA_cur = actor[jh * 512 + l31];
        float xaB_cur = actor[jh * 512 + 32 + l31];

#pragma unroll 1
        for (int jp = 0; jp < 8; ++jp) {
            // opaque zero: blocks hoist/CSE of wfrag reads across iterations
            int obf;
            asm volatile("v_mov_b32 %0, 0" : "=v"(obf));

            const float xaA = xaA_cur, xaB = xaB_cur;
            const int nbase = jh * 512 + ((jp + 1) & 7) * 64;
            xaA_cur = actor[nbase + l31];
            xaB_cur = actor[nbase + 32 + l31];
            const float xaAl = xaA - trunchi(xaA);
            const float xaBl = xaB - trunchi(xaB);

            // L0 B operands: k-slots (h=0): 0=actor, 1=actee, 2=1.0(bias)
            uint4 bAh4, bAl4, bBh4, bBl4;
            bAh4.x = pkhi(xaA, av);   bAh4.y = 0x00003F80u; bAh4.z = 0u; bAh4.w = 0u;
            bAl4.x = pkhi(xaAl, avl); bAl4.y = 0u;          bAl4.z = 0u; bAl4.w = 0u;
            bBh4.x = pkhi(xaB, av);   bBh4.y = 0x00003F80u; bBh4.z = 0u; bBh4.w = 0u;
            bBl4.x = pkhi(xaBl, avl); bBl4.y = 0u;          bBl4.z = 0u; bBl4.w = 0u;
            const short8 BAh = as_s8(bAh4), BAl = as_s8(bAl4);
            const short8 BBh = as_s8(bBh4), BBl = as_s8(bBl4);

            // ---- L0: 12 MFMA, W0ext frags shared from LDS (4 reads) ----
            const short8 W0h0 = LDSFRAGO(32), W0l0 = LDSFRAGO(33);
            const short8 W0h1 = LDSFRAGO(34), W0l1 = LDSFRAGO(35);
            v16f aA0, aA1, aB0, aB1;
            aA0 = MFMA(W0h0, BAh, zero16); aB0 = MFMA(W0h0, BBh, zero16);
            aA1 = MFMA(W0h1, BAh, zero16); aB1 = MFMA(W0h1, BBh, zero16);
            aA0 = MFMA(W0h0, BAl, aA0);    aB0 = MFMA(W0h0, BBl, aB0);
            aA1 = MFMA(W0h1, BAl, aA1);    aB1 = MFMA(W0h1, BBl, aB1);
            aA0 = MFMA(W0l0, BAh, aA0);    aB0 = MFMA(W0l0, BBh, aB0);
            aA1 = MFMA(W0l1, BAh, aA1);    aB1 = MFMA(W0l1, BBh, aB1);

            uint4 XAh[4], XAl[4], XBh[4], XBl[4];
            PACK_MT3(aA0, 0, XAh, XAl); PACK_MT3(aA1, 1, XAh, XAl);
            PACK_F3(aA0, XAh, XAl, inj);
            PACK_MT3(aB0, 0, XBh, XBl); PACK_MT3(aB1, 1, XBh, XBl);
            PACK_F3(aB0, XBh, XBl, inj);

            // ---- L1: 48 MFMA, 16 ds_read_b128 ----
            DUAL_CHAIN(0, XAh, XAl, XBh, XBl);
            PACK_MT3(aA0, 0, XAh, XAl); PACK_MT3(aA1, 1, XAh, XAl);
            PACK_F3(aA0, XAh, XAl, inj);
            PACK_MT3(aB0, 0, XBh, XBl); PACK_MT3(aB1, 1, XBh, XBl);
            PACK_F3(aB0, XBh, XBl, inj);

            // ---- L2: 48 MFMA, 16 ds_read_b128 ----
            DUAL_CHAIN(8, XAh, XAl, XBh, XBl);

            // ---- accumulate relu(h2), A first (r8 passing order) ----
#pragma unroll
            for (int r = 0; r < 14; ++r) sA0[r] += fmaxf(aA0[r], 0.f);
#pragma unroll
            for (int r = 0; r < 12; ++r) sA1[r] += fmaxf(aA1[r], 0.f);
#pragma unroll
            for (int r = 0; r < 14; ++r) sA0[r] += fmaxf(aB0[r], 0.f);
#pragma unroll
            for (int r = 0; r < 12; ++r) sA1[r] += fmaxf(aB1[r], 0.f);
        }

        // ---- deferred L3 for module m (fAcc phase-transient) ----
        {
            uint4 X3h[4], X3l[4];
            PACK_MT3(sA0, 0, X3h, X3l); PACK_MT3(sA1, 1, X3h, X3l);
            PACK_F3(sA0, X3h, X3l, inj16);   // 16 tiles/column -> bias x16

            const float* W3p = gW3 + m * H * F;
            const float* b3p = gb3 + m * F;
            v16f fAcc = (v16f)0.0f;
#pragma unroll
            for (int f = 0; f < 4; ++f) {
                unsigned hs[8], ls[8];
#pragma unroll
                for (int j = 0; j < 8; ++j) {
                    const int k = 16 * f + 8 * h + j;
                    float wv = 0.f;
                    if (l31 < F) {
                        if (k < H) wv = W3p[k * F + l31];
                        else if (k == H) wv = b3p[l31];    // bias row
                    }
                    unsigned uh = __float_as_uint(wv) & 0xFFFF0000u;
                    float lof = wv - __uint_as_float(uh);
                    hs[j] = uh;
                    ls[j] = __float_as_uint(lof) & 0xFFFF0000u;
                }
                uint4 hi, lo;
                hi.x = (hs[0] >> 16) | hs[1]; hi.y = (hs[2] >> 16) | hs[3];
                hi.z = (hs[4] >> 16) | hs[5]; hi.w = (hs[6] >> 16) | hs[7];
                lo.x = (ls[0] >> 16) | ls[1]; lo.y = (ls[2] >> 16) | ls[3];
                lo.z = (ls[4] >> 16) | ls[5]; lo.w = (ls[6] >> 16) | ls[7];
                const short8 ah = as_s8(hi), al = as_s8(lo);
                const short8 bh = as_s8(X3h[f]), bl = as_s8(X3l[f]);
                fAcc = MFMA(ah, bh, fAcc);
                fAcc = MFMA(ah, bl, fAcc);
                fAcc = MFMA(al, bh, fAcc);
            }

            // reduce this module's contribution into the LDS force buffer
#pragma unroll
            for (int r = 0; r < 16; ++r) {
                float v = fAcc[r];
                v += __shfl_xor(v, 1);
                v += __shfl_xor(v, 2);
                v += __shfl_xor(v, 4);
                v += __shfl_xor(v, 8);
                v += __shfl_xor(v, 16);
                const int row = (r & 3) + 8 * (r >> 2) + 4 * h;  // L3 feature
                if (l31 == 0 && row < F) atomicAdd(&fbuf[il][row], v);
            }
        }
        __syncthreads();   // atomics done + wfrag free before restaging
    }

    // ---- apply MLP in-block: wave 0 -> i_local 0, wave 1 -> i_local 1 ----
    if (w < 2) {
        const int al = w;
        const int io = blockIdx.x * 2 + al;
        const float* __restrict__ w0 = aW0 + c * F * H;   // (20,50)
        const float* __restrict__ b0 = ab0 + c * H;
        const float* __restrict__ w1 = aW1 + c * H;       // (50,1)
        float t = 0.f;
        if (lane < H) {
            float s = b0[lane];
#pragma unroll
            for (int k = 0; k < F; ++k) s = fmaf(fbuf[al][k], w0[k * H + lane], s);
            t = fmaxf(s, 0.f) * w1[lane];
        }
        t += __shfl_xor(t, 1);
        t += __shfl_xor(t, 2);
        t += __shfl_xor(t, 4);
        t += __shfl_xor(t, 8);
        t += __shfl_xor(t, 16);
        t += __shfl_xor(t, 32);
        if (lane == 0) out[c * NOBJ + io] = t + ab1[c];
    }
}

extern "C" void kernel_launch(void* const* d_in, const int* in_sizes, int n_in,
                              void* d_out, int out_size, void* d_ws, size_t ws_size,
                              hipStream_t stream) {
    const float* obj0  = (const float*)d_in[0];
    const float* obj1  = (const float*)d_in[1];
    const float* prev0 = (const float*)d_in[2];
    const float* prev1 = (const float*)d_in[3];
    const float* gW0 = (const float*)d_in[4];
    const float* gb0 = (const float*)d_in[5];
    const float* gW1 = (const float*)d_in[6];
    const float* gb1 = (const float*)d_in[7];
    const float* gW2 = (const float*)d_in[8];
    const float* gb2 = (const float*)d_in[9];
    const float* gW3 = (const float*)d_in[10];
    const float* gb3 = (const float*)d_in[11];
    const float* aW0 = (const float*)d_in[12];
    const float* ab0 = (const float*)d_in[13];
    const float* aW1 = (const float*)d_in[14];
    const float* ab1 = (const float*)d_in[15];

    dim3 grid(NOBJ / 2, 2);   // i-groups x actee class; 4 waves: 2 i x 2 j-halves
    fused_kernel<<<grid, 256, 0, stream>>>(obj0, obj1, prev0, prev1,
                                           gW0, gb0, gW1, gb1, gW2, gb2,
                                           gW3, gb3, aW0, ab0, aW1, ab1,
                                           (float*)d_out);
}

// Round 13
// 398.921 us; speedup vs baseline: 1.0534x; 1.0534x over previous
//
#include <hip/hip_runtime.h>

// PairwiseInteract, FINAL (revert to round-13/r10 — session-best graded 403us).
// Session verdict: two-pipe balanced plateau. VALUBusy ~ MfmaUtil ~ 60-66%
// across 2/3/4 waves/SIMD; split-bf16 pack VALU (~1000 cyc/tile/wave) is
// comparable to MFMA work (~1744 cyc/tile) and dependency-chained with it.
// Tested and bounded: occupancy 2/3/4w (+-3%), dual-tile ILP (-8%), split-term
// ILP (-18%), setprio (-9%), LDS traffic -50% (-8%), fusion (+2% graded),
// 8-wave blocks (-2%). Structure: single dispatch, blockIdx.y = actee class,
// a-loop staging module m=2a+c (36KB wfrag, opaque per-iteration LDS indices
// to stop loop-invariant hoisting -> 128 total regs), deferred per-module L3
// from global with per-phase LDS force reduction, in-block apply MLP.
// Algorithm: forces = (sum_j relu(h2)) @ W3 + 16*b3 per wave; split-bf16
// fp32 emulation (hh+hl+lh); f=3 k-frag packs specialized (neurons 51..63
// statically dead, k=50 carries the bias against an injected constant).

#define NOBJ 1024
#define H 50
#define F 20

using short8 = __attribute__((ext_vector_type(8))) short;
using v16f   = __attribute__((ext_vector_type(16))) float;

#define MFMA(A, B, C) __builtin_amdgcn_mfma_f32_32x32x16_bf16((A), (B), (C), 0, 0, 0)

__device__ __forceinline__ float trunchi(float x) {
    return __uint_as_float(__float_as_uint(x) & 0xFFFF0000u);
}
// dword = hi16(a) in low half | hi16(b) in high half
__device__ __forceinline__ unsigned pkhi(float a, float b) {
    return __builtin_amdgcn_perm(__float_as_uint(b), __float_as_uint(a), 0x07060302u);
}
__device__ __forceinline__ short8 as_s8(uint4 v) {
    union { uint4 u; short8 s; } x; x.u = v; return x.s;
}
// out-neuron at C slot (mt, tile-row l)
__device__ __forceinline__ int nu(int mt, int l) {
    return 16 * (l >> 3) + 8 * ((l >> 2) & 1) + 4 * mt + (l & 3);
}

// full pack for k-frags 0..2 (all 48 neurons real there)
#define PACK_MT3(ACC, MT, XH, XL)                                             \
    _Pragma("unroll") for (int f_ = 0; f_ < 3; ++f_) {                        \
        float r0 = fmaxf((ACC)[4 * f_ + 0], 0.f);                             \
        float r1 = fmaxf((ACC)[4 * f_ + 1], 0.f);                             \
        float r2 = fmaxf((ACC)[4 * f_ + 2], 0.f);                             \
        float r3 = fmaxf((ACC)[4 * f_ + 3], 0.f);                             \
        float l0 = r0 - trunchi(r0), l1 = r1 - trunchi(r1);                   \
        float l2 = r2 - trunchi(r2), l3 = r3 - trunchi(r3);                   \
        ((unsigned*)&(XH)[f_])[2 * (MT) + 0] = pkhi(r0, r1);                  \
        ((unsigned*)&(XH)[f_])[2 * (MT) + 1] = pkhi(r2, r3);                  \
        ((unsigned*)&(XL)[f_])[2 * (MT) + 0] = pkhi(l0, l1);                  \
        ((unsigned*)&(XL)[f_])[2 * (MT) + 1] = pkhi(l2, l3);                  \
    }

// k-frag 3: only k=48,49 (h=0) live activations; k=50 = injected bias mult.
#define PACK_F3(ACC0, XH, XL, INJ)                                            \
    {                                                                         \
        float r0_ = fmaxf((ACC0)[12], 0.f);                                   \
        float r1_ = fmaxf((ACC0)[13], 0.f);                                   \
        float l0_ = r0_ - trunchi(r0_), l1_ = r1_ - trunchi(r1_);             \
        (XH)[3].x = pkhi(r0_, r1_); (XL)[3].x = pkhi(l0_, l1_);               \
        (XH)[3].y = (INJ); (XL)[3].y = 0u;                                    \
        (XH)[3].z = 0u; (XH)[3].w = 0u;                                       \
        (XL)[3].z = 0u; (XL)[3].w = 0u;                                       \
    }

#define LDSFRAG(id)  (*(const short8*)&wfrag[(id) * 64 + lane])
// opaque-index variant: obf (==0, but opaque per-iteration) blocks hoist/CSE
#define LDSFRAGO(id) (*(const short8*)&wfrag[((id) + obf) * 64 + lane])

// hidden layer: 2 m-tiles x 4 k-frags x 3 split terms = 24 MFMA
#define LAYER_CHAIN(BASEC, XH, XL, A0, A1)                                    \
    _Pragma("unroll") for (int f_ = 0; f_ < 4; ++f_) {                        \
        short8 ah0 = LDSFRAGO(((BASEC) + f_) * 2 + 0);                        \
        short8 al0 = LDSFRAGO(((BASEC) + f_) * 2 + 1);                        \
        short8 ah1 = LDSFRAGO(((BASEC) + 4 + f_) * 2 + 0);                    \
        short8 al1 = LDSFRAGO(((BASEC) + 4 + f_) * 2 + 1);                    \
        short8 bh = as_s8((XH)[f_]), bl = as_s8((XL)[f_]);                    \
        if (f_ == 0) { A0 = MFMA(ah0, bh, zero16); A1 = MFMA(ah1, bh, zero16); } \
        else         { A0 = MFMA(ah0, bh, A0);     A1 = MFMA(ah1, bh, A1); }  \
        A0 = MFMA(ah0, bl, A0); A1 = MFMA(ah1, bl, A1);                       \
        A0 = MFMA(al0, bh, A0); A1 = MFMA(al1, bh, A1);                       \
    }

__global__ __launch_bounds__(256, 4)
void fused_kernel(const float* __restrict__ obj0, const float* __restrict__ obj1,
                  const float* __restrict__ prev0, const float* __restrict__ prev1,
                  const float* __restrict__ gW0, const float* __restrict__ gb0,
                  const float* __restrict__ gW1, const float* __restrict__ gb1,
                  const float* __restrict__ gW2, const float* __restrict__ gb2,
                  const float* __restrict__ gW3, const float* __restrict__ gb3,
                  const float* __restrict__ aW0, const float* __restrict__ ab0,
                  const float* __restrict__ aW1, const float* __restrict__ ab1,
                  float* __restrict__ out)
{
    // 36 pre-packed A-fragments (L1:0..15, L2:16..31, W0:32..35), 1KB each
    __shared__ uint4 wfrag[36 * 64];
    __shared__ float fbuf[2][F];     // per-block force accumulators

    const int w    = threadIdx.x >> 6;   // wave 0..3
    const int lane = threadIdx.x & 63;
    const int h    = lane >> 5;          // half-wave
    const int l31  = lane & 31;

    const int c  = blockIdx.y;           // actee class
    const int i  = blockIdx.x * 2 + (w >> 1);
    const int jh = w & 1;

    const float* actee = (c == 0) ? obj0 : obj1;
    const float av  = actee[i];
    const float avl = av - trunchi(av);
    const unsigned inj   = (h == 0) ? 0x00003F80u : 0u;   // 1.0 bf16 at k=50
    const unsigned inj16 = (h == 0) ? 0x00004180u : 0u;   // 16.0 bf16 at k=50

    if (threadIdx.x < 2 * F) ((float*)fbuf)[threadIdx.x] = 0.f;

    const v16f zero16 = (v16f)0.0f;

#pragma unroll 1
    for (int a = 0; a < 4; ++a) {
        const int m = a * 2 + c;         // module
        const float* actor = (a == 0) ? obj0 : (a == 1) ? obj1
                           : (a == 2) ? prev0 : prev1;

        // ---- stage W0/W1/W2 split-bf16 A-fragments for module m ----
        for (int combo = w; combo < 18; combo += 4) {
            const int layer = (combo < 8) ? 1 : (combo < 16) ? 2 : 0;
            const float* W; const float* b; int ncols, col, mt, f, krows;
            if (layer == 1) {
                const int rel = combo;
                W = gW1 + m * H * H; b = gb1 + m * H; ncols = H; krows = H;
                mt = rel >> 2; f = rel & 3; col = nu(mt, l31);
            } else if (layer == 2) {
                const int rel = combo - 8;
                W = gW2 + m * H * H; b = gb2 + m * H; ncols = H; krows = H;
                mt = rel >> 2; f = rel & 3; col = nu(mt, l31);
            } else {
                const int rel = combo - 16;
                W = gW0 + m * 2 * H; b = gb0 + m * H; ncols = H; krows = 2;
                mt = rel; f = 0; col = nu(mt, l31);
            }
            unsigned hs[8], ls[8];
#pragma unroll
            for (int j = 0; j < 8; ++j) {
                const int k = 16 * f + 8 * h + j;
                float wv = 0.f;
                if (col < ncols) {
                    if (k < krows) wv = W[k * ncols + col];
                    else if (k == krows) wv = b[col];      // bias row
                }
                unsigned uh = __float_as_uint(wv) & 0xFFFF0000u;
                float lof = wv - __uint_as_float(uh);
                hs[j] = uh;
                ls[j] = __float_as_uint(lof) & 0xFFFF0000u;
            }
            uint4 hi, lo;
            hi.x = (hs[0] >> 16) | hs[1]; hi.y = (hs[2] >> 16) | hs[3];
            hi.z = (hs[4] >> 16) | hs[5]; hi.w = (hs[6] >> 16) | hs[7];
            lo.x = (ls[0] >> 16) | ls[1]; lo.y = (ls[2] >> 16) | ls[3];
            lo.z = (ls[4] >> 16) | ls[5]; lo.w = (ls[6] >> 16) | ls[7];
            wfrag[(combo * 2 + 0) * 64 + lane] = hi;
            wfrag[(combo * 2 + 1) * 64 + lane] = lo;
        }
        __syncthreads();                 // staging visible to all waves

        v16f sA0 = (v16f)0.0f, sA1 = (v16f)0.0f;   // sum of relu(h2)
        float xa_cur = actor[jh * 512 + l31];

#pragma unroll 1
        for (int jt = 0; jt < 16; ++jt) {
            // opaque zero: blocks hoist/CSE of wfrag reads across iterations
            int obf;
            asm volatile("v_mov_b32 %0, 0" : "=v"(obf));

            const float xa = xa_cur;
            xa_cur = actor[jh * 512 + ((jt + 1) & 15) * 32 + l31];
            const float xal = xa - trunchi(xa);

            // L0 B operand: k-slots (h=0): 0=actor, 1=actee, 2=1.0(bias)
            uint4 b0h4, b0l4;
            b0h4.x = pkhi(xa, av);   b0h4.y = 0x00003F80u; b0h4.z = 0u; b0h4.w = 0u;
            b0l4.x = pkhi(xal, avl); b0l4.y = 0u;          b0l4.z = 0u; b0l4.w = 0u;
            const short8 B0h = as_s8(b0h4), B0l = as_s8(b0l4);

            // ---- L0: 6 MFMA, W0ext frags streamed from LDS ----
            const short8 W0h0 = LDSFRAGO(32), W0l0 = LDSFRAGO(33);
            const short8 W0h1 = LDSFRAGO(34), W0l1 = LDSFRAGO(35);
            v16f a0, a1;
            a0 = MFMA(W0h0, B0h, zero16); a1 = MFMA(W0h1, B0h, zero16);
            a0 = MFMA(W0h0, B0l, a0);     a1 = MFMA(W0h1, B0l, a1);
            a0 = MFMA(W0l0, B0h, a0);     a1 = MFMA(W0l1, B0h, a1);

            uint4 X1h[4], X1l[4];
            PACK_MT3(a0, 0, X1h, X1l); PACK_MT3(a1, 1, X1h, X1l);
            PACK_F3(a0, X1h, X1l, inj);

            // ---- L1: 24 MFMA ----
            LAYER_CHAIN(0, X1h, X1l, a0, a1);
            uint4 X2h[4], X2l[4];
            PACK_MT3(a0, 0, X2h, X2l); PACK_MT3(a1, 1, X2h, X2l);
            PACK_F3(a0, X2h, X2l, inj);

            // ---- L2: 24 MFMA ----
            LAYER_CHAIN(8, X2h, X2l, a0, a1);

            // ---- accumulate relu(h2) (dead slots skipped statically) ----
#pragma unroll
            for (int r = 0; r < 14; ++r) sA0[r] += fmaxf(a0[r], 0.f);
#pragma unroll
            for (int r = 0; r < 12; ++r) sA1[r] += fmaxf(a1[r], 0.f);
        }

        // ---- deferred L3 for module m (fAcc phase-transient) ----
        {
            uint4 X3h[4], X3l[4];
            PACK_MT3(sA0, 0, X3h, X3l); PACK_MT3(sA1, 1, X3h, X3l);
            PACK_F3(sA0, X3h, X3l, inj16);   // 16 tiles/column -> bias x16

            const float* W3p = gW3 + m * H * F;
            const float* b3p = gb3 + m * F;
            v16f fAcc = (v16f)0.0f;
#pragma unroll
            for (int f = 0; f < 4; ++f) {
                unsigned hs[8], ls[8];
#pragma unroll
                for (int j = 0; j < 8; ++j) {
                    const int k = 16 * f + 8 * h + j;
                    float wv = 0.f;
                    if (l31 < F) {
                        if (k < H) wv = W3p[k * F + l31];
                        else if (k == H) wv = b3p[l31];    // bias row
                    }
                    unsigned uh = __float_as_uint(wv) & 0xFFFF0000u;
                    float lof = wv - __uint_as_float(uh);
                    hs[j] = uh;
                    ls[j] = __float_as_uint(lof) & 0xFFFF0000u;
                }
                uint4 hi, lo;
                hi.x = (hs[0] >> 16) | hs[1]; hi.y = (hs[2] >> 16) | hs[3];
                hi.z = (hs[4] >> 16) | hs[5]; hi.w = (hs[6] >> 16) | hs[7];
                lo.x = (ls[0] >> 16) | ls[1]; lo.y = (ls[2] >> 16) | ls[3];
                lo.z = (ls[4] >> 16) | ls[5]; lo.w = (ls[6] >> 16) | ls[7];
                const short8 ah = as_s8(hi), al = as_s8(lo);
                const short8 bh = as_s8(X3h[f]), bl = as_s8(X3l[f]);
                fAcc = MFMA(ah, bh, fAcc);
                fAcc = MFMA(ah, bl, fAcc);
                fAcc = MFMA(al, bh, fAcc);
            }

            // reduce this module's contribution into the LDS force buffer
#pragma unroll
            for (int r = 0; r < 16; ++r) {
                float v = fAcc[r];
                v += __shfl_xor(v, 1);
                v += __shfl_xor(v, 2);
                v += __shfl_xor(v, 4);
                v += __shfl_xor(v, 8);
                v += __shfl_xor(v, 16);
                const int row = (r & 3) + 8 * (r >> 2) + 4 * h;  // L3 feature
                if (l31 == 0 && row < F) atomicAdd(&fbuf[w >> 1][row], v);
            }
        }
        __syncthreads();   // atomics done + wfrag free before restaging
    }

    // ---- apply MLP in-block: wave 0 -> i_local 0, wave 1 -> i_local 1 ----
    if (w < 2) {
        const int il = w;
        const int io = blockIdx.x * 2 + il;
        const float* __restrict__ w0 = aW0 + c * F * H;   // (20,50)
        const float* __restrict__ b0 = ab0 + c * H;
        const float* __restrict__ w1 = aW1 + c * H;       // (50,1)
        float t = 0.f;
        if (lane < H) {
            float s = b0[lane];
#pragma unroll
            for (int k = 0; k < F; ++k) s = fmaf(fbuf[il][k], w0[k * H + lane], s);
            t = fmaxf(s, 0.f) * w1[lane];
        }
        t += __shfl_xor(t, 1);
        t += __shfl_xor(t, 2);
        t += __shfl_xor(t, 4);
        t += __shfl_xor(t, 8);
        t += __shfl_xor(t, 16);
        t += __shfl_xor(t, 32);
        if (lane == 0) out[c * NOBJ + io] = t + ab1[c];
    }
}

extern "C" void kernel_launch(void* const* d_in, const int* in_sizes, int n_in,
                              void* d_out, int out_size, void* d_ws, size_t ws_size,
                              hipStream_t stream) {
    const float* obj0  = (const float*)d_in[0];
    const float* obj1  = (const float*)d_in[1];
    const float* prev0 = (const float*)d_in[2];
    const float* prev1 = (const float*)d_in[3];
    const float* gW0 = (const float*)d_in[4];
    const float* gb0 = (const float*)d_in[5];
    const float* gW1 = (const float*)d_in[6];
    const float* gb1 = (const float*)d_in[7];
    const float* gW2 = (const float*)d_in[8];
    const float* gb2 = (const float*)d_in[9];
    const float* gW3 = (const float*)d_in[10];
    const float* gb3 = (const float*)d_in[11];
    const float* aW0 = (const float*)d_in[12];
    const float* ab0 = (const float*)d_in[13];
    const float* aW1 = (const float*)d_in[14];
    const float* ab1 = (const float*)d_in[15];

    dim3 grid(NOBJ / 2, 2);   // i-groups x actee class; 4 waves: 2 i x 2 j-halves
    fused_kernel<<<grid, 256, 0, stream>>>(obj0, obj1, prev0, prev1,
                                           gW0, gb0, gW1, gb1, gW2, gb2,
                                           gW3, gb3, aW0, ab0, aW1, ab1,
                                           (float*)d_out);
}